// Round 7
// baseline (297.331 us; speedup 1.0000x reference)
//
#include <hip/hip_runtime.h>
#include <math.h>

typedef __attribute__((ext_vector_type(4))) float f32x4;
typedef __attribute__((ext_vector_type(4))) _Float16 f16x4;

#define B_  16
#define D_  2048
#define H_  16
#define HD_ 128
#define LP_ 2048
#define M_  8192
#define QKV_R (3 * D_)
#define SCALE 0.08838834764831845f   // 1/sqrt(128)
#define NSPLIT 64
#define KPS 32    // keys per split
#define CHK 4     // rows per register chunk
#define NCH (KPS / CHK)   // 8 chunks

__device__ inline float wave_sum(float v) {
  for (int m = 32; m > 0; m >>= 1) v += __shfl_xor(v, m);
  return v;
}

// ---------------- LayerNorm: one block per batch row, 256 threads ----------
__global__ void ln_kernel(const float* __restrict__ x, const float* __restrict__ w,
                          const float* __restrict__ bb, float* __restrict__ o) {
  __shared__ float sred[4];
  int b = blockIdx.x, t = threadIdx.x;
  const float* xr = x + (size_t)b * D_;
  f32x4 v0 = *(const f32x4*)(xr + t * 8);
  f32x4 v1 = *(const f32x4*)(xr + t * 8 + 4);
  float s = (v0[0] + v0[1] + v0[2] + v0[3]) + (v1[0] + v1[1] + v1[2] + v1[3]);
  s = wave_sum(s);
  if ((t & 63) == 0) sred[t >> 6] = s;
  __syncthreads();
  float mu = (sred[0] + sred[1] + sred[2] + sred[3]) * (1.0f / D_);
  __syncthreads();
  float sq = 0.f;
  for (int i = 0; i < 4; i++) {
    float d0 = v0[i] - mu; sq += d0 * d0;
    float d1 = v1[i] - mu; sq += d1 * d1;
  }
  sq = wave_sum(sq);
  if ((t & 63) == 0) sred[t >> 6] = sq;
  __syncthreads();
  float var = (sred[0] + sred[1] + sred[2] + sred[3]) * (1.0f / D_);
  float rs = rsqrtf(var + 1e-5f);
  f32x4 w0 = *(const f32x4*)(w + t * 8), w1 = *(const f32x4*)(w + t * 8 + 4);
  f32x4 c0 = *(const f32x4*)(bb + t * 8), c1 = *(const f32x4*)(bb + t * 8 + 4);
  f32x4 o0, o1;
  for (int i = 0; i < 4; i++) {
    o0[i] = (v0[i] - mu) * rs * w0[i] + c0[i];
    o1[i] = (v1[i] - mu) * rs * w1[i] + c1[i];
  }
  *(f32x4*)(o + (size_t)b * D_ + t * 8) = o0;
  *(f32x4*)(o + (size_t)b * D_ + t * 8 + 4) = o1;
}

// ---------------- Skinny GEMM: C[16,R] = X[16,K] @ W[R,K]^T ----------------
__global__ void gemv_k(const float* __restrict__ W, const float* __restrict__ X,
                       float* __restrict__ part, int R, int K, int kc) {
  int wave = threadIdx.x >> 6, lane = threadIdx.x & 63;
  int j0 = (blockIdx.x * 4 + wave) * 16;
  int k0 = blockIdx.y * kc;
  int col = lane & 15;
  int kg  = (lane >> 4) << 2;
  const float* wp = W + (size_t)(j0 + col) * K + k0 + kg;
  const float* xp = X + (size_t)col * K + k0 + kg;
  f32x4 acc = {0.f, 0.f, 0.f, 0.f};
  #pragma unroll 4
  for (int kk = 0; kk < kc; kk += 16) {
    f32x4 av = *(const f32x4*)xp; xp += 16;
    f32x4 bv = __builtin_nontemporal_load((const f32x4*)wp); wp += 16;
    f16x4 ah, bh;
    for (int i = 0; i < 4; i++) { ah[i] = (_Float16)av[i]; bh[i] = (_Float16)bv[i]; }
    acc = __builtin_amdgcn_mfma_f32_16x16x16f16(ah, bh, acc, 0, 0, 0);
  }
  *(f32x4*)(part + ((size_t)blockIdx.y * R + j0 + col) * 16 + kg) = acc;
}

// ---------------- split-K reduce + epilogues -------------------------------
__global__ void reduce_plain(const float* __restrict__ part, float* __restrict__ out,
                             int R, int S) {
  int i = blockIdx.x * 256 + threadIdx.x;
  int j = i >> 4, b = i & 15;
  float s = 0.f;
  for (int k = 0; k < S; k++) s += part[(size_t)k * R * 16 + i];
  out[(size_t)b * R + j] = s;
}
__global__ void reduce_resid(const float* __restrict__ part, const float* __restrict__ resid,
                             float* __restrict__ out, int R, int S) {
  int i = blockIdx.x * 256 + threadIdx.x;
  int j = i >> 4, b = i & 15;
  float s = 0.f;
  for (int k = 0; k < S; k++) s += part[(size_t)k * R * 16 + i];
  out[(size_t)b * R + j] = resid[(size_t)b * R + j] + s;
}
__global__ void reduce_bias_gelu(const float* __restrict__ part, const float* __restrict__ bias,
                                 float* __restrict__ out, int R, int S) {
  int i = blockIdx.x * 256 + threadIdx.x;
  int j = i >> 4, b = i & 15;
  float s = 0.f;
  for (int k = 0; k < S; k++) s += part[(size_t)k * R * 16 + i];
  float u = s + bias[j];
  out[(size_t)b * R + j] = 0.5f * u * (1.0f + erff(u * 0.70710678118654752f));
}
__global__ void reduce_bias_resid(const float* __restrict__ part, const float* __restrict__ bias,
                                  const float* __restrict__ resid, float* __restrict__ out,
                                  int R, int S) {
  int i = blockIdx.x * 256 + threadIdx.x;
  int j = i >> 4, b = i & 15;
  float s = 0.f;
  for (int k = 0; k < S; k++) s += part[(size_t)k * R * 16 + i];
  out[(size_t)b * R + j] = resid[(size_t)b * R + j] + s + bias[j];
}

// ---------------- attention pass 1: scores, register-dbuf K stream ---------
// grid (B, NSPLIT), 256 threads, 4 blocks/CU (16 waves/CU). Per iteration:
// issue 8 nontemporal dwordx4 loads for chunk c+1, sched_barrier, consume
// chunk c (compiler emits counted vmcnt(8)). 8-16 KB in flight per wave.
__global__ void __launch_bounds__(256, 4)
attn_scores(const float* __restrict__ qkv, const float* __restrict__ pk,
            float* __restrict__ scores) {
  int b = blockIdx.x, sp = blockIdx.y;
  int t = threadIdx.x;
  int h = t >> 4, d8 = (t & 15) * 8;
  __shared__ float s_t[H_][KPS + 1];

  f32x4 q0 = *(const f32x4*)(qkv + (size_t)b * QKV_R + h * HD_ + d8);
  f32x4 q1 = *(const f32x4*)(qkv + (size_t)b * QKV_R + h * HD_ + d8 + 4);
  for (int i = 0; i < 4; i++) { q0[i] *= SCALE; q1[i] *= SCALE; }

  const float* kb = pk + ((size_t)b * LP_ + (size_t)sp * KPS) * D_ + t * 8;
  f32x4 ka[2][CHK], kc[2][CHK];
  #pragma unroll
  for (int c = 0; c < CHK; c++) {
    ka[0][c] = __builtin_nontemporal_load((const f32x4*)(kb + (size_t)c * D_));
    kc[0][c] = __builtin_nontemporal_load((const f32x4*)(kb + (size_t)c * D_ + 4));
  }
  #pragma unroll
  for (int ch = 0; ch < NCH; ++ch) {
    const int cur = ch & 1, nxt = cur ^ 1;
    if (ch + 1 < NCH) {
      #pragma unroll
      for (int c = 0; c < CHK; c++) {
        size_t off = (size_t)((ch + 1) * CHK + c) * D_;
        ka[nxt][c] = __builtin_nontemporal_load((const f32x4*)(kb + off));
        kc[nxt][c] = __builtin_nontemporal_load((const f32x4*)(kb + off + 4));
      }
    }
    __builtin_amdgcn_sched_barrier(0);
    #pragma unroll
    for (int c = 0; c < CHK; c++) {
      float s = q0[0]*ka[cur][c][0] + q0[1]*ka[cur][c][1]
              + q0[2]*ka[cur][c][2] + q0[3]*ka[cur][c][3]
              + q1[0]*kc[cur][c][0] + q1[1]*kc[cur][c][1]
              + q1[2]*kc[cur][c][2] + q1[3]*kc[cur][c][3];
      s += __shfl_xor(s, 1); s += __shfl_xor(s, 2);
      s += __shfl_xor(s, 4); s += __shfl_xor(s, 8);
      if ((t & 15) == 0) s_t[h][ch * CHK + c] = s;
    }
  }
  __syncthreads();
  if ((t & 15) < KPS / 4) {
    int l4 = (t & 15) * 4;
    f32x4 o;
    for (int i = 0; i < 4; i++) o[i] = s_t[h][l4 + i];
    *(f32x4*)(scores + (size_t)(b * H_ + h) * LP_ + (size_t)sp * KPS + l4) = o;
  }
}

// ---------------- attention pass 2: softmax over 2048+1 -------------------
__global__ void attn_soft(const float* __restrict__ qkv, float* __restrict__ scores,
                          float* __restrict__ pml) {
  int bh = blockIdx.x, b = bh >> 4, h = bh & 15;
  int t = threadIdx.x;
  __shared__ float sred[4];
  float prod = 0.f;
  if (t < 128) {
    float qv = qkv[(size_t)b * QKV_R + h * HD_ + t];
    float kn = qkv[(size_t)b * QKV_R + D_ + h * HD_ + t];
    prod = qv * kn;
  }
  prod = wave_sum(prod);
  if ((t & 63) == 0) sred[t >> 6] = prod;
  __syncthreads();
  float s_new = (sred[0] + sred[1] + sred[2] + sred[3]) * SCALE;
  __syncthreads();
  float* sp = scores + (size_t)bh * LP_;
  f32x4 v0 = *(const f32x4*)(sp + t * 8);
  f32x4 v1 = *(const f32x4*)(sp + t * 8 + 4);
  float m = s_new;
  for (int i = 0; i < 4; i++) m = fmaxf(m, fmaxf(v0[i], v1[i]));
  for (int mm = 32; mm > 0; mm >>= 1) m = fmaxf(m, __shfl_xor(m, mm));
  if ((t & 63) == 0) sred[t >> 6] = m;
  __syncthreads();
  float M = fmaxf(fmaxf(sred[0], sred[1]), fmaxf(sred[2], sred[3]));
  __syncthreads();
  float ls = 0.f;
  for (int i = 0; i < 4; i++) {
    v0[i] = __expf(v0[i] - M); ls += v0[i];
    v1[i] = __expf(v1[i] - M); ls += v1[i];
  }
  ls = wave_sum(ls);
  if ((t & 63) == 0) sred[t >> 6] = ls;
  __syncthreads();
  float en = __expf(s_new - M);
  float L = sred[0] + sred[1] + sred[2] + sred[3] + en;
  float inv = 1.0f / L;
  for (int i = 0; i < 4; i++) { v0[i] *= inv; v1[i] *= inv; }
  *(f32x4*)(sp + t * 8) = v0;
  *(f32x4*)(sp + t * 8 + 4) = v1;
  if (t == 0) pml[bh] = en * inv;
}

// ---------------- attention pass 3: A@V, register-dbuf V stream ------------
__global__ void __launch_bounds__(256, 4)
attn_av(const float* __restrict__ scores, const float* __restrict__ pv,
        float* __restrict__ pacc) {
  int b = blockIdx.x, sp = blockIdx.y;
  int t = threadIdx.x;
  int h = t >> 4, d8 = (t & 15) * 8;
  __shared__ float p_l[H_][KPS + 1];

  if ((t & 15) < KPS / 4) {
    int l4 = (t & 15) * 4;
    f32x4 pr = *(const f32x4*)(scores + (size_t)(b * H_ + h) * LP_ + (size_t)sp * KPS + l4);
    for (int i = 0; i < 4; i++) p_l[h][l4 + i] = pr[i];
  }
  __syncthreads();

  const float* vb = pv + ((size_t)b * LP_ + (size_t)sp * KPS) * D_ + t * 8;
  f32x4 va[2][CHK], vc[2][CHK];
  #pragma unroll
  for (int c = 0; c < CHK; c++) {
    va[0][c] = __builtin_nontemporal_load((const f32x4*)(vb + (size_t)c * D_));
    vc[0][c] = __builtin_nontemporal_load((const f32x4*)(vb + (size_t)c * D_ + 4));
  }
  f32x4 a0 = {0.f, 0.f, 0.f, 0.f}, a1 = {0.f, 0.f, 0.f, 0.f};
  #pragma unroll
  for (int ch = 0; ch < NCH; ++ch) {
    const int cur = ch & 1, nxt = cur ^ 1;
    if (ch + 1 < NCH) {
      #pragma unroll
      for (int c = 0; c < CHK; c++) {
        size_t off = (size_t)((ch + 1) * CHK + c) * D_;
        va[nxt][c] = __builtin_nontemporal_load((const f32x4*)(vb + off));
        vc[nxt][c] = __builtin_nontemporal_load((const f32x4*)(vb + off + 4));
      }
    }
    __builtin_amdgcn_sched_barrier(0);
    #pragma unroll
    for (int c = 0; c < CHK; c++) {
      float p = p_l[h][ch * CHK + c];
      for (int i = 0; i < 4; i++) {
        a0[i] += p * va[cur][c][i];
        a1[i] += p * vc[cur][c][i];
      }
    }
  }
  size_t oi = (((size_t)b * NSPLIT + sp) * H_ + h) * HD_ + d8;
  *(f32x4*)(pacc + oi) = a0;
  *(f32x4*)(pacc + oi + 4) = a1;
}

// ---------------- combine partials + new token -----------------------------
__global__ void attn_comb(const float* __restrict__ qkv, const float* __restrict__ pml,
                          const float* __restrict__ pacc, float* __restrict__ attn_out) {
  int bh = blockIdx.x, b = bh >> 4, h = bh & 15;
  int t = threadIdx.x;  // 128
  float o = 0.f;
  for (int s = 0; s < NSPLIT; s++)
    o += pacc[(((size_t)b * NSPLIT + s) * H_ + h) * HD_ + t];
  o += pml[bh] * qkv[(size_t)b * QKV_R + 2 * D_ + h * HD_ + t];
  attn_out[(size_t)b * D_ + h * HD_ + t] = o;
}

extern "C" void kernel_launch(void* const* d_in, const int* in_sizes, int n_in,
                              void* d_out, int out_size, void* d_ws, size_t ws_size,
                              hipStream_t stream) {
  const float* input  = (const float*)d_in[0];
  const float* pk     = (const float*)d_in[1];
  const float* pv     = (const float*)d_in[2];
  const float* ln0_w  = (const float*)d_in[3];
  const float* ln0_b  = (const float*)d_in[4];
  const float* ln1_w  = (const float*)d_in[5];
  const float* ln1_b  = (const float*)d_in[6];
  const float* wqkv   = (const float*)d_in[7];
  const float* wo     = (const float*)d_in[8];
  const float* fc0_w  = (const float*)d_in[9];
  const float* fc0_b  = (const float*)d_in[10];
  const float* fc1_w  = (const float*)d_in[11];
  const float* fc1_b  = (const float*)d_in[12];
  float* out = (float*)d_out;

  char* wsb = (char*)d_ws;
  float* x_ln     = (float*)(wsb + 0);         // 16x2048           128 KB
  float* qkv      = (float*)(wsb + 131072);    // 16x6144           384 KB
  float* attn_out = (float*)(wsb + 524288);    // 16x2048           128 KB
  float* hbuf     = (float*)(wsb + 655360);    // 16x2048           128 KB
  float* y0       = (float*)(wsb + 786432);    // 16x2048           128 KB
  float* act      = (float*)(wsb + 917504);    // 16x8192           512 KB
  float* scores   = (float*)(wsb + 1441792);   // 16x16x2048          2 MB
  float* pml      = (float*)(wsb + 3538944);   // 16x16               4 KB
  float* pacc     = (float*)(wsb + 3543040);   // 64x16x16x128        8 MB
  float* part     = (float*)(wsb + 11931648);  // up to 8*6144*16     3 MB

  // 1. LN0
  ln_kernel<<<16, 256, 0, stream>>>(input, ln0_w, ln0_b, x_ln);
  // 2. QKV projection (R=6144, K=2048, split 8)
  gemv_k<<<dim3(96, 8), 256, 0, stream>>>(wqkv, x_ln, part, QKV_R, D_, 256);
  reduce_plain<<<384, 256, 0, stream>>>(part, qkv, QKV_R, 8);
  // 3. attention: scores -> softmax -> A@V -> combine
  attn_scores<<<dim3(B_, NSPLIT), 256, 0, stream>>>(qkv, pk, scores);
  attn_soft<<<256, 256, 0, stream>>>(qkv, scores, pml);
  attn_av<<<dim3(B_, NSPLIT), 256, 0, stream>>>(scores, pv, pacc);
  attn_comb<<<256, 128, 0, stream>>>(qkv, pml, pacc, attn_out);
  // 4. output projection + residual (R=2048, K=2048, split 16)
  gemv_k<<<dim3(32, 16), 256, 0, stream>>>(wo, attn_out, part, D_, D_, 128);
  reduce_resid<<<128, 256, 0, stream>>>(part, input, hbuf, D_, 16);
  // 5. LN1
  ln_kernel<<<16, 256, 0, stream>>>(hbuf, ln1_w, ln1_b, y0);
  // 6. FC0 + gelu (R=8192, K=2048, split 4)
  gemv_k<<<dim3(128, 4), 256, 0, stream>>>(fc0_w, y0, part, M_, D_, 512);
  reduce_bias_gelu<<<512, 256, 0, stream>>>(part, fc0_b, act, M_, 4);
  // 7. FC1 + bias + residual (R=2048, K=8192, split 16)
  gemv_k<<<dim3(32, 16), 256, 0, stream>>>(fc1_w, act, part, D_, M_, 512);
  reduce_bias_resid<<<128, 256, 0, stream>>>(part, fc1_b, hbuf, out, D_, 16);
}

// Round 8
// 207.146 us; speedup vs baseline: 1.4354x; 1.4354x over previous
//
#include <hip/hip_runtime.h>
#include <math.h>

typedef __attribute__((ext_vector_type(4))) float f32x4;
typedef __attribute__((ext_vector_type(4))) _Float16 f16x4;

#define B_  16
#define D_  2048
#define H_  16
#define HD_ 128
#define LP_ 2048
#define M_  8192
#define QKV_R (3 * D_)
#define SCALE 0.08838834764831845f   // 1/sqrt(128)
#define NSPLIT 64
#define KPW 32        // key rows per block (one wave)
#define DEPTH 4       // LDS ring slots (8 KB each), 3 rows prefetch-ahead

__device__ inline float wave_sum(float v) {
  for (int m = 32; m > 0; m >>= 1) v += __shfl_xor(v, m);
  return v;
}

__device__ inline void gl_lds16(const float* g, float* l) {
  __builtin_amdgcn_global_load_lds(
      (const __attribute__((address_space(1))) void*)g,
      (__attribute__((address_space(3))) void*)l, 16, 0, 0);
}

// Stage one 8 KB key row into ring slot (linear LDS dest, source pre-swizzled
// with the involution swz(x) = x ^ (((x>>7)&7)<<4) so swizzled reads are
// bank-spread; rule: gl_lds dest must be linear, swizzle goes on src+read).
__device__ inline void stage_row(const float* rowbase, float* ringrow, int lane) {
  #pragma unroll
  for (int j = 0; j < 8; j++) {
    int x  = j * 1024 + lane * 16;            // linear byte offset in row
    int sx = x ^ (((x >> 7) & 7) << 4);       // involution
    gl_lds16(rowbase + (sx >> 2), ringrow + j * 256);
  }
}

// Read lane's 32-float chunk (head h = lane>>2, d0 = (lane&3)*32) from a
// swizzle-staged ring row.
__device__ inline void read_row(const float* ringrow, int lane, f32x4 kv[8]) {
  #pragma unroll
  for (int j = 0; j < 8; j++) {
    int fo = lane * 32 + ((j ^ (lane & 7)) << 2);
    kv[j] = *(const f32x4*)(ringrow + fo);
  }
}

// ---------------- LayerNorm: one block per batch row, 256 threads ----------
__global__ void ln_kernel(const float* __restrict__ x, const float* __restrict__ w,
                          const float* __restrict__ bb, float* __restrict__ o) {
  __shared__ float sred[4];
  int b = blockIdx.x, t = threadIdx.x;
  const float* xr = x + (size_t)b * D_;
  f32x4 v0 = *(const f32x4*)(xr + t * 8);
  f32x4 v1 = *(const f32x4*)(xr + t * 8 + 4);
  float s = (v0[0] + v0[1] + v0[2] + v0[3]) + (v1[0] + v1[1] + v1[2] + v1[3]);
  s = wave_sum(s);
  if ((t & 63) == 0) sred[t >> 6] = s;
  __syncthreads();
  float mu = (sred[0] + sred[1] + sred[2] + sred[3]) * (1.0f / D_);
  __syncthreads();
  float sq = 0.f;
  for (int i = 0; i < 4; i++) {
    float d0 = v0[i] - mu; sq += d0 * d0;
    float d1 = v1[i] - mu; sq += d1 * d1;
  }
  sq = wave_sum(sq);
  if ((t & 63) == 0) sred[t >> 6] = sq;
  __syncthreads();
  float var = (sred[0] + sred[1] + sred[2] + sred[3]) * (1.0f / D_);
  float rs = rsqrtf(var + 1e-5f);
  f32x4 w0 = *(const f32x4*)(w + t * 8), w1 = *(const f32x4*)(w + t * 8 + 4);
  f32x4 c0 = *(const f32x4*)(bb + t * 8), c1 = *(const f32x4*)(bb + t * 8 + 4);
  f32x4 o0, o1;
  for (int i = 0; i < 4; i++) {
    o0[i] = (v0[i] - mu) * rs * w0[i] + c0[i];
    o1[i] = (v1[i] - mu) * rs * w1[i] + c1[i];
  }
  *(f32x4*)(o + (size_t)b * D_ + t * 8) = o0;
  *(f32x4*)(o + (size_t)b * D_ + t * 8 + 4) = o1;
}

// ---------------- Skinny GEMM: C[16,R] = X[16,K] @ W[R,K]^T ----------------
__global__ void gemv_k(const float* __restrict__ W, const float* __restrict__ X,
                       float* __restrict__ part, int R, int K, int kc) {
  int wave = threadIdx.x >> 6, lane = threadIdx.x & 63;
  int j0 = (blockIdx.x * 4 + wave) * 16;
  int k0 = blockIdx.y * kc;
  int col = lane & 15;
  int kg  = (lane >> 4) << 2;
  const float* wp = W + (size_t)(j0 + col) * K + k0 + kg;
  const float* xp = X + (size_t)col * K + k0 + kg;
  f32x4 acc = {0.f, 0.f, 0.f, 0.f};
  #pragma unroll 4
  for (int kk = 0; kk < kc; kk += 16) {
    f32x4 av = *(const f32x4*)xp; xp += 16;
    f32x4 bv = *(const f32x4*)wp; wp += 16;
    f16x4 ah, bh;
    for (int i = 0; i < 4; i++) { ah[i] = (_Float16)av[i]; bh[i] = (_Float16)bv[i]; }
    acc = __builtin_amdgcn_mfma_f32_16x16x16f16(ah, bh, acc, 0, 0, 0);
  }
  *(f32x4*)(part + ((size_t)blockIdx.y * R + j0 + col) * 16 + kg) = acc;
}

// ---------------- split-K reduce + epilogues -------------------------------
__global__ void reduce_plain(const float* __restrict__ part, float* __restrict__ out,
                             int R, int S) {
  int i = blockIdx.x * 256 + threadIdx.x;
  int j = i >> 4, b = i & 15;
  float s = 0.f;
  for (int k = 0; k < S; k++) s += part[(size_t)k * R * 16 + i];
  out[(size_t)b * R + j] = s;
}
__global__ void reduce_resid(const float* __restrict__ part, const float* __restrict__ resid,
                             float* __restrict__ out, int R, int S) {
  int i = blockIdx.x * 256 + threadIdx.x;
  int j = i >> 4, b = i & 15;
  float s = 0.f;
  for (int k = 0; k < S; k++) s += part[(size_t)k * R * 16 + i];
  out[(size_t)b * R + j] = resid[(size_t)b * R + j] + s;
}
__global__ void reduce_bias_gelu(const float* __restrict__ part, const float* __restrict__ bias,
                                 float* __restrict__ out, int R, int S) {
  int i = blockIdx.x * 256 + threadIdx.x;
  int j = i >> 4, b = i & 15;
  float s = 0.f;
  for (int k = 0; k < S; k++) s += part[(size_t)k * R * 16 + i];
  float u = s + bias[j];
  out[(size_t)b * R + j] = 0.5f * u * (1.0f + erff(u * 0.70710678118654752f));
}
__global__ void reduce_bias_resid(const float* __restrict__ part, const float* __restrict__ bias,
                                  const float* __restrict__ resid, float* __restrict__ out,
                                  int R, int S) {
  int i = blockIdx.x * 256 + threadIdx.x;
  int j = i >> 4, b = i & 15;
  float s = 0.f;
  for (int k = 0; k < S; k++) s += part[(size_t)k * R * 16 + i];
  out[(size_t)b * R + j] = resid[(size_t)b * R + j] + s + bias[j];
}

// ---------------- attention pass 1: scores, per-wave LDS ring --------------
// grid (B, NSPLIT), 64 threads (ONE wave). Private 4-slot ring of 8 KB rows,
// 3 rows prefetch-ahead, counted vmcnt, ZERO barriers. Lane l: head h=l>>2,
// d0=(l&3)*32.
__global__ void attn_scores(const float* __restrict__ qkv, const float* __restrict__ pk,
                            float* __restrict__ scores) {
  int b = blockIdx.x, sp = blockIdx.y;
  int lane = threadIdx.x;
  __shared__ float ring[DEPTH][D_];
  __shared__ float s_t[H_][KPW + 1];

  // q chunk: 32 floats at qkv[b][lane*32] (== [h][d0..d0+32]), pre-scaled
  f32x4 q[8];
  #pragma unroll
  for (int j = 0; j < 8; j++) {
    q[j] = *(const f32x4*)(qkv + (size_t)b * QKV_R + lane * 32 + j * 4);
    for (int i = 0; i < 4; i++) q[j][i] *= SCALE;
  }

  const float* gbase = pk + ((size_t)b * LP_ + (size_t)sp * KPW) * D_;
  stage_row(gbase + 0 * D_, ring[0], lane);
  stage_row(gbase + 1 * D_, ring[1], lane);
  stage_row(gbase + 2 * D_, ring[2], lane);

  for (int r = 0; r < KPW; ++r) {
    if (r + 3 < KPW) {
      stage_row(gbase + (size_t)(r + 3) * D_, ring[(r + 3) & (DEPTH - 1)], lane);
      __builtin_amdgcn_sched_barrier(0);
      asm volatile("s_waitcnt vmcnt(24)" ::: "memory");
    } else if (r == KPW - 3) {
      asm volatile("s_waitcnt vmcnt(16)" ::: "memory");
    } else if (r == KPW - 2) {
      asm volatile("s_waitcnt vmcnt(8)" ::: "memory");
    } else {
      asm volatile("s_waitcnt vmcnt(0)" ::: "memory");
    }
    __builtin_amdgcn_sched_barrier(0);
    f32x4 kv[8];
    read_row(ring[r & (DEPTH - 1)], lane, kv);
    float s = 0.f;
    #pragma unroll
    for (int j = 0; j < 8; j++)
      s += q[j][0]*kv[j][0] + q[j][1]*kv[j][1] + q[j][2]*kv[j][2] + q[j][3]*kv[j][3];
    s += __shfl_xor(s, 1);
    s += __shfl_xor(s, 2);
    if ((lane & 3) == 0) s_t[lane >> 2][r] = s;
  }
  // coalesced write-out: scores[b][h][sp*KPW + i]
  #pragma unroll
  for (int half = 0; half < 2; half++) {
    int h = lane >> 2, i4 = (lane & 3) * 4 + half * 16;
    f32x4 o;
    for (int i = 0; i < 4; i++) o[i] = s_t[h][i4 + i];
    *(f32x4*)(scores + (size_t)(b * H_ + h) * LP_ + (size_t)sp * KPW + i4) = o;
  }
}

// ---------------- attention pass 2: softmax over 2048+1 -------------------
__global__ void attn_soft(const float* __restrict__ qkv, float* __restrict__ scores,
                          float* __restrict__ pml) {
  int bh = blockIdx.x, b = bh >> 4, h = bh & 15;
  int t = threadIdx.x;
  __shared__ float sred[4];
  float prod = 0.f;
  if (t < 128) {
    float qv = qkv[(size_t)b * QKV_R + h * HD_ + t];
    float kn = qkv[(size_t)b * QKV_R + D_ + h * HD_ + t];
    prod = qv * kn;
  }
  prod = wave_sum(prod);
  if ((t & 63) == 0) sred[t >> 6] = prod;
  __syncthreads();
  float s_new = (sred[0] + sred[1] + sred[2] + sred[3]) * SCALE;
  __syncthreads();
  float* sp = scores + (size_t)bh * LP_;
  f32x4 v0 = *(const f32x4*)(sp + t * 8);
  f32x4 v1 = *(const f32x4*)(sp + t * 8 + 4);
  float m = s_new;
  for (int i = 0; i < 4; i++) m = fmaxf(m, fmaxf(v0[i], v1[i]));
  for (int mm = 32; mm > 0; mm >>= 1) m = fmaxf(m, __shfl_xor(m, mm));
  if ((t & 63) == 0) sred[t >> 6] = m;
  __syncthreads();
  float M = fmaxf(fmaxf(sred[0], sred[1]), fmaxf(sred[2], sred[3]));
  __syncthreads();
  float ls = 0.f;
  for (int i = 0; i < 4; i++) {
    v0[i] = __expf(v0[i] - M); ls += v0[i];
    v1[i] = __expf(v1[i] - M); ls += v1[i];
  }
  ls = wave_sum(ls);
  if ((t & 63) == 0) sred[t >> 6] = ls;
  __syncthreads();
  float en = __expf(s_new - M);
  float L = sred[0] + sred[1] + sred[2] + sred[3] + en;
  float inv = 1.0f / L;
  for (int i = 0; i < 4; i++) { v0[i] *= inv; v1[i] *= inv; }
  *(f32x4*)(sp + t * 8) = v0;
  *(f32x4*)(sp + t * 8 + 4) = v1;
  if (t == 0) pml[bh] = en * inv;
}

// ---------------- attention pass 3: A@V, per-wave LDS ring -----------------
__global__ void attn_av(const float* __restrict__ scores, const float* __restrict__ pv,
                        float* __restrict__ pacc) {
  int b = blockIdx.x, sp = blockIdx.y;
  int lane = threadIdx.x;
  __shared__ float ring[DEPTH][D_];
  __shared__ float p_l[H_][KPW + 1];

  // stage this block's normalized probs: 16 heads x KPW keys
  #pragma unroll
  for (int half = 0; half < 2; half++) {
    int h = lane >> 2, i4 = (lane & 3) * 4 + half * 16;
    f32x4 pr = *(const f32x4*)(scores + (size_t)(b * H_ + h) * LP_ + (size_t)sp * KPW + i4);
    for (int i = 0; i < 4; i++) p_l[h][i4 + i] = pr[i];
  }

  const float* gbase = pv + ((size_t)b * LP_ + (size_t)sp * KPW) * D_;
  stage_row(gbase + 0 * D_, ring[0], lane);
  stage_row(gbase + 1 * D_, ring[1], lane);
  stage_row(gbase + 2 * D_, ring[2], lane);

  int h = lane >> 2;
  f32x4 a[8];
  #pragma unroll
  for (int j = 0; j < 8; j++) a[j] = (f32x4){0.f, 0.f, 0.f, 0.f};

  for (int r = 0; r < KPW; ++r) {
    if (r + 3 < KPW) {
      stage_row(gbase + (size_t)(r + 3) * D_, ring[(r + 3) & (DEPTH - 1)], lane);
      __builtin_amdgcn_sched_barrier(0);
      asm volatile("s_waitcnt vmcnt(24)" ::: "memory");
    } else if (r == KPW - 3) {
      asm volatile("s_waitcnt vmcnt(16)" ::: "memory");
    } else if (r == KPW - 2) {
      asm volatile("s_waitcnt vmcnt(8)" ::: "memory");
    } else {
      asm volatile("s_waitcnt vmcnt(0)" ::: "memory");
    }
    __builtin_amdgcn_sched_barrier(0);
    f32x4 kv[8];
    read_row(ring[r & (DEPTH - 1)], lane, kv);
    float p = p_l[h][r];
    #pragma unroll
    for (int j = 0; j < 8; j++)
      for (int i = 0; i < 4; i++) a[j][i] += p * kv[j][i];
  }
  // lane's 32-float chunk of pacc[b][sp][h][d0..d0+32], coalesced
  float* ob = pacc + (((size_t)b * NSPLIT + sp) * H_ + h) * HD_ + (lane & 3) * 32;
  #pragma unroll
  for (int j = 0; j < 8; j++) *(f32x4*)(ob + j * 4) = a[j];
}

// ---------------- combine partials + new token -----------------------------
__global__ void attn_comb(const float* __restrict__ qkv, const float* __restrict__ pml,
                          const float* __restrict__ pacc, float* __restrict__ attn_out) {
  int bh = blockIdx.x, b = bh >> 4, h = bh & 15;
  int t = threadIdx.x;  // 128
  float o = 0.f;
  for (int s = 0; s < NSPLIT; s++)
    o += pacc[(((size_t)b * NSPLIT + s) * H_ + h) * HD_ + t];
  o += pml[bh] * qkv[(size_t)b * QKV_R + 2 * D_ + h * HD_ + t];
  attn_out[(size_t)b * D_ + h * HD_ + t] = o;
}

extern "C" void kernel_launch(void* const* d_in, const int* in_sizes, int n_in,
                              void* d_out, int out_size, void* d_ws, size_t ws_size,
                              hipStream_t stream) {
  const float* input  = (const float*)d_in[0];
  const float* pk     = (const float*)d_in[1];
  const float* pv     = (const float*)d_in[2];
  const float* ln0_w  = (const float*)d_in[3];
  const float* ln0_b  = (const float*)d_in[4];
  const float* ln1_w  = (const float*)d_in[5];
  const float* ln1_b  = (const float*)d_in[6];
  const float* wqkv   = (const float*)d_in[7];
  const float* wo     = (const float*)d_in[8];
  const float* fc0_w  = (const float*)d_in[9];
  const float* fc0_b  = (const float*)d_in[10];
  const float* fc1_w  = (const float*)d_in[11];
  const float* fc1_b  = (const float*)d_in[12];
  float* out = (float*)d_out;

  char* wsb = (char*)d_ws;
  float* x_ln     = (float*)(wsb + 0);         // 16x2048           128 KB
  float* qkv      = (float*)(wsb + 131072);    // 16x6144           384 KB
  float* attn_out = (float*)(wsb + 524288);    // 16x2048           128 KB
  float* hbuf     = (float*)(wsb + 655360);    // 16x2048           128 KB
  float* y0       = (float*)(wsb + 786432);    // 16x2048           128 KB
  float* act      = (float*)(wsb + 917504);    // 16x8192           512 KB
  float* scores   = (float*)(wsb + 1441792);   // 16x16x2048          2 MB
  float* pml      = (float*)(wsb + 3538944);   // 16x16               4 KB
  float* pacc     = (float*)(wsb + 3543040);   // 64x16x16x128        8 MB
  float* part     = (float*)(wsb + 11931648);  // up to 8*6144*16     3 MB

  // 1. LN0
  ln_kernel<<<16, 256, 0, stream>>>(input, ln0_w, ln0_b, x_ln);
  // 2. QKV projection (R=6144, K=2048, split 8)
  gemv_k<<<dim3(96, 8), 256, 0, stream>>>(wqkv, x_ln, part, QKV_R, D_, 256);
  reduce_plain<<<384, 256, 0, stream>>>(part, qkv, QKV_R, 8);
  // 3. attention: scores -> softmax -> A@V -> combine
  attn_scores<<<dim3(B_, NSPLIT), 64, 0, stream>>>(qkv, pk, scores);
  attn_soft<<<256, 256, 0, stream>>>(qkv, scores, pml);
  attn_av<<<dim3(B_, NSPLIT), 64, 0, stream>>>(scores, pv, pacc);
  attn_comb<<<256, 128, 0, stream>>>(qkv, pml, pacc, attn_out);
  // 4. output projection + residual (R=2048, K=2048, split 16)
  gemv_k<<<dim3(32, 16), 256, 0, stream>>>(wo, attn_out, part, D_, D_, 128);
  reduce_resid<<<128, 256, 0, stream>>>(part, input, hbuf, D_, 16);
  // 5. LN1
  ln_kernel<<<16, 256, 0, stream>>>(hbuf, ln1_w, ln1_b, y0);
  // 6. FC0 + gelu (R=8192, K=2048, split 4)
  gemv_k<<<dim3(128, 4), 256, 0, stream>>>(fc0_w, y0, part, M_, D_, 512);
  reduce_bias_gelu<<<512, 256, 0, stream>>>(part, fc0_b, act, M_, 4);
  // 7. FC1 + bias + residual (R=2048, K=8192, split 16)
  gemv_k<<<dim3(32, 16), 256, 0, stream>>>(fc1_w, act, part, D_, M_, 512);
  reduce_bias_resid<<<128, 256, 0, stream>>>(part, fc1_b, hbuf, out, D_, 16);
}

// Round 9
// 205.304 us; speedup vs baseline: 1.4482x; 1.0090x over previous
//
#include <hip/hip_runtime.h>
#include <math.h>

typedef __attribute__((ext_vector_type(4))) float f32x4;
typedef __attribute__((ext_vector_type(4))) _Float16 f16x4;

#define B_  16
#define D_  2048
#define H_  16
#define HD_ 128
#define LP_ 2048
#define M_  8192
#define QKV_R (3 * D_)
#define SCALE 0.08838834764831845f   // 1/sqrt(128)
#define NSPLIT 32
#define KPS 64    // keys per split
#define TROWS 4   // key rows per LDS tile (32 KB)
#define NT (KPS / TROWS)

__device__ inline float wave_sum(float v) {
  for (int m = 32; m > 0; m >>= 1) v += __shfl_xor(v, m);
  return v;
}

// global->LDS direct, 16B/lane, NT policy: K/V are single-use streams -- keep
// them OUT of L3 so the 201 MB of weights stays resident across replays.
__device__ inline void gl_lds16(const float* g, float* l) {
  __builtin_amdgcn_global_load_lds(
      (const __attribute__((address_space(1))) void*)g,
      (__attribute__((address_space(3))) void*)l, 16, 0, 2 /*NT*/);
}

// ---------------- LayerNorm (ln0): one block per batch row -----------------
__global__ void ln_kernel(const float* __restrict__ x, const float* __restrict__ w,
                          const float* __restrict__ bb, float* __restrict__ o) {
  __shared__ float sred[4];
  int b = blockIdx.x, t = threadIdx.x;
  const float* xr = x + (size_t)b * D_;
  f32x4 v0 = *(const f32x4*)(xr + t * 8);
  f32x4 v1 = *(const f32x4*)(xr + t * 8 + 4);
  float s = (v0[0] + v0[1] + v0[2] + v0[3]) + (v1[0] + v1[1] + v1[2] + v1[3]);
  s = wave_sum(s);
  if ((t & 63) == 0) sred[t >> 6] = s;
  __syncthreads();
  float mu = (sred[0] + sred[1] + sred[2] + sred[3]) * (1.0f / D_);
  __syncthreads();
  float sq = 0.f;
  for (int i = 0; i < 4; i++) {
    float d0 = v0[i] - mu; sq += d0 * d0;
    float d1 = v1[i] - mu; sq += d1 * d1;
  }
  sq = wave_sum(sq);
  if ((t & 63) == 0) sred[t >> 6] = sq;
  __syncthreads();
  float var = (sred[0] + sred[1] + sred[2] + sred[3]) * (1.0f / D_);
  float rs = rsqrtf(var + 1e-5f);
  f32x4 w0 = *(const f32x4*)(w + t * 8), w1 = *(const f32x4*)(w + t * 8 + 4);
  f32x4 c0 = *(const f32x4*)(bb + t * 8), c1 = *(const f32x4*)(bb + t * 8 + 4);
  f32x4 o0, o1;
  for (int i = 0; i < 4; i++) {
    o0[i] = (v0[i] - mu) * rs * w0[i] + c0[i];
    o1[i] = (v1[i] - mu) * rs * w1[i] + c1[i];
  }
  *(f32x4*)(o + (size_t)b * D_ + t * 8) = o0;
  *(f32x4*)(o + (size_t)b * D_ + t * 8 + 4) = o1;
}

// ---------------- Skinny GEMM: C[16,R] = X[16,K] @ W[R,K]^T ----------------
// Plain (cached) loads: weights total ~201 MB < 256 MB L3 -> resident across
// replays once K/V streams stop thrashing (they are NT).
__global__ void gemv_k(const float* __restrict__ W, const float* __restrict__ X,
                       float* __restrict__ part, int R, int K, int kc) {
  int wave = threadIdx.x >> 6, lane = threadIdx.x & 63;
  int j0 = (blockIdx.x * 4 + wave) * 16;
  int k0 = blockIdx.y * kc;
  int col = lane & 15;
  int kg  = (lane >> 4) << 2;
  const float* wp = W + (size_t)(j0 + col) * K + k0 + kg;
  const float* xp = X + (size_t)col * K + k0 + kg;
  f32x4 acc = {0.f, 0.f, 0.f, 0.f};
  #pragma unroll 4
  for (int kk = 0; kk < kc; kk += 16) {
    f32x4 av = *(const f32x4*)xp; xp += 16;
    f32x4 bv = *(const f32x4*)wp; wp += 16;
    f16x4 ah, bh;
    for (int i = 0; i < 4; i++) { ah[i] = (_Float16)av[i]; bh[i] = (_Float16)bv[i]; }
    acc = __builtin_amdgcn_mfma_f32_16x16x16f16(ah, bh, acc, 0, 0, 0);
  }
  *(f32x4*)(part + ((size_t)blockIdx.y * R + j0 + col) * 16 + kg) = acc;
}

// ---------------- split-K reduce + epilogues -------------------------------
__global__ void reduce_plain(const float* __restrict__ part, float* __restrict__ out,
                             int R, int S) {
  int i = blockIdx.x * 256 + threadIdx.x;
  int j = i >> 4, b = i & 15;
  float s = 0.f;
  for (int k = 0; k < S; k++) s += part[(size_t)k * R * 16 + i];
  out[(size_t)b * R + j] = s;
}
__global__ void reduce_bias_gelu(const float* __restrict__ part, const float* __restrict__ bias,
                                 float* __restrict__ out, int R, int S) {
  int i = blockIdx.x * 256 + threadIdx.x;
  int j = i >> 4, b = i & 15;
  float s = 0.f;
  for (int k = 0; k < S; k++) s += part[(size_t)k * R * 16 + i];
  float u = s + bias[j];
  out[(size_t)b * R + j] = 0.5f * u * (1.0f + erff(u * 0.70710678118654752f));
}
__global__ void reduce_bias_resid(const float* __restrict__ part, const float* __restrict__ bias,
                                  const float* __restrict__ resid, float* __restrict__ out,
                                  int R, int S) {
  int i = blockIdx.x * 256 + threadIdx.x;
  int j = i >> 4, b = i & 15;
  float s = 0.f;
  for (int k = 0; k < S; k++) s += part[(size_t)k * R * 16 + i];
  out[(size_t)b * R + j] = resid[(size_t)b * R + j] + s + bias[j];
}

// ---- fused: h = input + wo_out (split-K reduce) ; y0 = LN1(h) -------------
// one block per batch row; thread t owns j = t + 256*i, i=0..7
__global__ void reduce_resid_ln(const float* __restrict__ part, const float* __restrict__ input,
                                const float* __restrict__ w, const float* __restrict__ bb,
                                float* __restrict__ hbuf, float* __restrict__ y0) {
  __shared__ float sred[4];
  int b = blockIdx.x, t = threadIdx.x;
  float h[8];
  float lsum = 0.f;
  #pragma unroll
  for (int i = 0; i < 8; i++) {
    int j = t + 256 * i;
    float s = 0.f;
    for (int k = 0; k < 16; k++) s += part[((size_t)k * D_ + j) * 16 + b];
    h[i] = input[(size_t)b * D_ + j] + s;
    lsum += h[i];
  }
  lsum = wave_sum(lsum);
  if ((t & 63) == 0) sred[t >> 6] = lsum;
  __syncthreads();
  float mu = (sred[0] + sred[1] + sred[2] + sred[3]) * (1.0f / D_);
  __syncthreads();
  float sq = 0.f;
  #pragma unroll
  for (int i = 0; i < 8; i++) { float d = h[i] - mu; sq += d * d; }
  sq = wave_sum(sq);
  if ((t & 63) == 0) sred[t >> 6] = sq;
  __syncthreads();
  float var = (sred[0] + sred[1] + sred[2] + sred[3]) * (1.0f / D_);
  float rs = rsqrtf(var + 1e-5f);
  #pragma unroll
  for (int i = 0; i < 8; i++) {
    int j = t + 256 * i;
    hbuf[(size_t)b * D_ + j] = h[i];
    y0[(size_t)b * D_ + j] = (h[i] - mu) * rs * w[j] + bb[j];
  }
}

// ---------------- attention pass 1: scores via LDS-staged K stream ---------
__global__ void attn_scores(const float* __restrict__ qkv, const float* __restrict__ pk,
                            float* __restrict__ scores) {
  int b = blockIdx.x, sp = blockIdx.y;
  int t = threadIdx.x;
  int wv = __builtin_amdgcn_readfirstlane(threadIdx.x) >> 6;
  int lane = t & 63;
  int h = t >> 4, d8 = (t & 15) * 8;
  __shared__ float kbuf[2][TROWS][D_];
  __shared__ float s_t[H_][KPS + 1];

  f32x4 q0 = *(const f32x4*)(qkv + (size_t)b * QKV_R + h * HD_ + d8);
  f32x4 q1 = *(const f32x4*)(qkv + (size_t)b * QKV_R + h * HD_ + d8 + 4);
  for (int i = 0; i < 4; i++) { q0[i] *= SCALE; q1[i] *= SCALE; }

  const float* gbase = pk + ((size_t)b * LP_ + (size_t)sp * KPS) * D_;
  auto stage = [&](int buf, int tile) {
    const float* src = gbase + (size_t)tile * (TROWS * D_) + wv * 2048 + lane * 4;
    float* dst = &kbuf[buf][0][0] + wv * 2048;
    #pragma unroll
    for (int j = 0; j < 8; j++) gl_lds16(src + j * 256, dst + j * 256);
  };

  stage(0, 0);
  for (int tile = 0; tile < NT; ++tile) {
    int cur = tile & 1;
    if (tile + 1 < NT) {
      stage(cur ^ 1, tile + 1);
      __builtin_amdgcn_sched_barrier(0);
      asm volatile("s_waitcnt vmcnt(8)" ::: "memory");
    } else {
      __builtin_amdgcn_sched_barrier(0);
      asm volatile("s_waitcnt vmcnt(0)" ::: "memory");
    }
    __builtin_amdgcn_s_barrier();
    __builtin_amdgcn_sched_barrier(0);
    #pragma unroll
    for (int r = 0; r < TROWS; ++r) {
      const float* kr = &kbuf[cur][r][h * HD_ + d8];
      f32x4 k0 = *(const f32x4*)kr;
      f32x4 k1 = *(const f32x4*)(kr + 4);
      float s = q0[0]*k0[0] + q0[1]*k0[1] + q0[2]*k0[2] + q0[3]*k0[3]
              + q1[0]*k1[0] + q1[1]*k1[1] + q1[2]*k1[2] + q1[3]*k1[3];
      s += __shfl_xor(s, 1); s += __shfl_xor(s, 2);
      s += __shfl_xor(s, 4); s += __shfl_xor(s, 8);
      if ((t & 15) == 0) s_t[h][tile * TROWS + r] = s;
    }
    asm volatile("" ::: "memory");
    __builtin_amdgcn_s_barrier();
  }
  __syncthreads();
  {
    int l4 = (t & 15) * 4;
    f32x4 o;
    for (int i = 0; i < 4; i++) o[i] = s_t[h][l4 + i];
    *(f32x4*)(scores + (size_t)(b * H_ + h) * LP_ + (size_t)sp * KPS + l4) = o;
  }
}

// ---------------- attention pass 2: A@V with in-kernel split softmax -------
// Flash-style: per (head, split) compute m,l over the 64 raw scores, p=exp(s-m),
// unnormalized partial acc -> pacc; (m,l) -> pml. Combine rescales.
__global__ void attn_av(const float* __restrict__ scores, const float* __restrict__ pv,
                        float* __restrict__ pacc, float* __restrict__ pml) {
  int b = blockIdx.x, sp = blockIdx.y;
  int t = threadIdx.x;
  int wv = __builtin_amdgcn_readfirstlane(threadIdx.x) >> 6;
  int lane = t & 63;
  int h = t >> 4, d8 = (t & 15) * 8;
  __shared__ float vbuf[2][TROWS][D_];
  __shared__ float p_l[H_][KPS + 1];

  {  // per-split softmax partials from raw scores (16 lanes x 4 keys per head)
    int l4 = (t & 15) * 4;
    f32x4 sc = *(const f32x4*)(scores + (size_t)(b * H_ + h) * LP_ + (size_t)sp * KPS + l4);
    float m = fmaxf(fmaxf(sc[0], sc[1]), fmaxf(sc[2], sc[3]));
    m = fmaxf(m, __shfl_xor(m, 1)); m = fmaxf(m, __shfl_xor(m, 2));
    m = fmaxf(m, __shfl_xor(m, 4)); m = fmaxf(m, __shfl_xor(m, 8));
    f32x4 p;
    float ls = 0.f;
    for (int i = 0; i < 4; i++) { p[i] = __expf(sc[i] - m); ls += p[i]; }
    ls += __shfl_xor(ls, 1); ls += __shfl_xor(ls, 2);
    ls += __shfl_xor(ls, 4); ls += __shfl_xor(ls, 8);
    for (int i = 0; i < 4; i++) p_l[h][l4 + i] = p[i];
    if ((t & 15) == 0) {
      pml[((b * NSPLIT + sp) * H_ + h) * 2]     = m;
      pml[((b * NSPLIT + sp) * H_ + h) * 2 + 1] = ls;
    }
  }

  const float* gbase = pv + ((size_t)b * LP_ + (size_t)sp * KPS) * D_;
  auto stage = [&](int buf, int tile) {
    const float* src = gbase + (size_t)tile * (TROWS * D_) + wv * 2048 + lane * 4;
    float* dst = &vbuf[buf][0][0] + wv * 2048;
    #pragma unroll
    for (int j = 0; j < 8; j++) gl_lds16(src + j * 256, dst + j * 256);
  };

  stage(0, 0);
  __syncthreads();   // p_l visible (also drains tile-0 stage; prologue only)

  f32x4 a0 = {0.f, 0.f, 0.f, 0.f}, a1 = {0.f, 0.f, 0.f, 0.f};
  for (int tile = 0; tile < NT; ++tile) {
    int cur = tile & 1;
    if (tile + 1 < NT) {
      stage(cur ^ 1, tile + 1);
      __builtin_amdgcn_sched_barrier(0);
      asm volatile("s_waitcnt vmcnt(8)" ::: "memory");
    } else {
      __builtin_amdgcn_sched_barrier(0);
      asm volatile("s_waitcnt vmcnt(0)" ::: "memory");
    }
    __builtin_amdgcn_s_barrier();
    __builtin_amdgcn_sched_barrier(0);
    #pragma unroll
    for (int r = 0; r < TROWS; ++r) {
      float p = p_l[h][tile * TROWS + r];
      const float* vr = &vbuf[cur][r][h * HD_ + d8];
      f32x4 v0 = *(const f32x4*)vr;
      f32x4 v1 = *(const f32x4*)(vr + 4);
      for (int i = 0; i < 4; i++) { a0[i] += p * v0[i]; a1[i] += p * v1[i]; }
    }
    asm volatile("" ::: "memory");
    __builtin_amdgcn_s_barrier();
  }
  size_t oi = (((size_t)b * NSPLIT + sp) * H_ + h) * HD_ + d8;
  *(f32x4*)(pacc + oi) = a0;
  *(f32x4*)(pacc + oi + 4) = a1;
}

// ---------------- combine splits + fold in new token's K/V -----------------
__global__ void attn_comb(const float* __restrict__ qkv, const float* __restrict__ pml,
                          const float* __restrict__ pacc, float* __restrict__ attn_out) {
  int bh = blockIdx.x, b = bh >> 4, hh = bh & 15;
  int t = threadIdx.x;  // 128
  __shared__ float sred[2];
  float qv = qkv[(size_t)b * QKV_R + hh * HD_ + t];
  float kn = qkv[(size_t)b * QKV_R + D_ + hh * HD_ + t];
  float d = qv * kn;
  d = wave_sum(d);
  if ((t & 63) == 0) sred[t >> 6] = d;
  __syncthreads();
  float s_new = (sred[0] + sred[1]) * SCALE;
  float vn = qkv[(size_t)b * QKV_R + 2 * D_ + hh * HD_ + t];
  float M = s_new;
  for (int s = 0; s < NSPLIT; s++)
    M = fmaxf(M, pml[((b * NSPLIT + s) * H_ + hh) * 2]);
  float en = __expf(s_new - M);
  float L = en;
  float o = en * vn;
  for (int s = 0; s < NSPLIT; s++) {
    float ms = pml[((b * NSPLIT + s) * H_ + hh) * 2];
    float ls = pml[((b * NSPLIT + s) * H_ + hh) * 2 + 1];
    float e = __expf(ms - M);
    L += ls * e;
    o += pacc[(((size_t)b * NSPLIT + s) * H_ + hh) * HD_ + t] * e;
  }
  attn_out[(size_t)b * D_ + hh * HD_ + t] = o / L;
}

extern "C" void kernel_launch(void* const* d_in, const int* in_sizes, int n_in,
                              void* d_out, int out_size, void* d_ws, size_t ws_size,
                              hipStream_t stream) {
  const float* input  = (const float*)d_in[0];
  const float* pk     = (const float*)d_in[1];
  const float* pv     = (const float*)d_in[2];
  const float* ln0_w  = (const float*)d_in[3];
  const float* ln0_b  = (const float*)d_in[4];
  const float* ln1_w  = (const float*)d_in[5];
  const float* ln1_b  = (const float*)d_in[6];
  const float* wqkv   = (const float*)d_in[7];
  const float* wo     = (const float*)d_in[8];
  const float* fc0_w  = (const float*)d_in[9];
  const float* fc0_b  = (const float*)d_in[10];
  const float* fc1_w  = (const float*)d_in[11];
  const float* fc1_b  = (const float*)d_in[12];
  float* out = (float*)d_out;

  char* wsb = (char*)d_ws;
  float* x_ln     = (float*)(wsb + 0);         // 16x2048           128 KB
  float* qkv      = (float*)(wsb + 131072);    // 16x6144           384 KB
  float* attn_out = (float*)(wsb + 524288);    // 16x2048           128 KB
  float* hbuf     = (float*)(wsb + 655360);    // 16x2048           128 KB
  float* y0       = (float*)(wsb + 786432);    // 16x2048           128 KB
  float* act      = (float*)(wsb + 917504);    // 16x8192           512 KB
  float* scores   = (float*)(wsb + 1441792);   // 16x16x2048          2 MB
  float* pml      = (float*)(wsb + 3538944);   // 16x32x16x2         64 KB
  float* pacc     = (float*)(wsb + 3604480);   // 32x16x16x128        4 MB
  float* part     = (float*)(wsb + 11931648);  // up to 8*6144*16     3 MB

  // 1. LN0
  ln_kernel<<<16, 256, 0, stream>>>(input, ln0_w, ln0_b, x_ln);
  // 2. QKV projection (R=6144, K=2048, split 8)
  gemv_k<<<dim3(96, 8), 256, 0, stream>>>(wqkv, x_ln, part, QKV_R, D_, 256);
  reduce_plain<<<384, 256, 0, stream>>>(part, qkv, QKV_R, 8);
  // 3. attention: scores -> (softmax folded into) A@V -> combine
  attn_scores<<<dim3(B_, NSPLIT), 256, 0, stream>>>(qkv, pk, scores);
  attn_av<<<dim3(B_, NSPLIT), 256, 0, stream>>>(scores, pv, pacc, pml);
  attn_comb<<<256, 128, 0, stream>>>(qkv, pml, pacc, attn_out);
  // 4. output projection (R=2048, K=2048, split 16) + fused residual+LN1
  gemv_k<<<dim3(32, 16), 256, 0, stream>>>(wo, attn_out, part, D_, D_, 128);
  reduce_resid_ln<<<16, 256, 0, stream>>>(part, input, ln1_w, ln1_b, hbuf, y0);
  // 5. FC0 + gelu (R=8192, K=2048, split 4)
  gemv_k<<<dim3(128, 4), 256, 0, stream>>>(fc0_w, y0, part, M_, D_, 512);
  reduce_bias_gelu<<<512, 256, 0, stream>>>(part, fc0_b, act, M_, 4);
  // 6. FC1 + bias + residual (R=2048, K=8192, split 16)
  gemv_k<<<dim3(32, 16), 256, 0, stream>>>(fc1_w, act, part, D_, M_, 512);
  reduce_bias_resid<<<128, 256, 0, stream>>>(part, fc1_b, hbuf, out, D_, 16);
}